// Round 6
// baseline (1017.109 us; speedup 1.0000x reference)
//
#include <hip/hip_runtime.h>

// Problem: B=2, L=2048, EMB=1024, HEADS=16, HDIM=64
//   out  = [B,L,E] fp32   (d_out[0 .. 4194304))
//   attn = [B,H,L,L] fp32 (d_out[4194304 .. 138412032))
// Workspace layout (needs ~33.8 MB):
//   qk_ws  bf16 [4096][2048]      (q cols 0..1023, k cols 1024..2047)
//   vt_ws  bf16 [32][64][2048]    (v transposed: [b*16+h][d][l])
//   ao_ws  bf16 [4096][1024]      (attention output, pre-projection)
//   rowsum f32  [32][2048]

typedef __attribute__((ext_vector_type(8))) short bf16x8;
typedef __attribute__((ext_vector_type(4))) float f32x4;
typedef __attribute__((ext_vector_type(2))) unsigned int u32x2;

__device__ __forceinline__ unsigned short f2bf(float f) {
  unsigned int u = __float_as_uint(f);
  u += 0x7fffu + ((u >> 16) & 1u);   // RNE
  return (unsigned short)(u >> 16);
}

// ---------------- K1: qkv = x @ w_qkv^T  (M=4096, N=3072, K=1024) ----------------
__global__ __launch_bounds__(256) void gemm_qkv(
    const float* __restrict__ X, const float* __restrict__ W,
    unsigned short* __restrict__ qk_ws, unsigned short* __restrict__ vt_ws) {
  __shared__ unsigned short smem[2 * 128 * 72];
  unsigned short* a_lds = smem;
  unsigned short* b_lds = smem + 128 * 72;
  const int tid = threadIdx.x;
  const int lane = tid & 63;
  const int wid = tid >> 6;
  const int wm = wid >> 1, wn = wid & 1;           // 2x2 waves, 64x64 each
  const int m0 = blockIdx.x * 128;                 // token tile
  const int n0 = blockIdx.y * 128;                 // feature tile

  f32x4 acc[4][4];
#pragma unroll
  for (int i = 0; i < 4; ++i)
#pragma unroll
    for (int j = 0; j < 4; ++j) acc[i][j] = (f32x4){0.f, 0.f, 0.f, 0.f};

  for (int kt = 0; kt < 16; ++kt) {
    const int k0 = kt * 64;
#pragma unroll
    for (int i = 0; i < 8; ++i) {                  // stage A and B (fp32 -> bf16)
      const int c = i * 256 + tid;
      const int row = c >> 4, cc = c & 15;
      float4 va = *(const float4*)(X + (size_t)(m0 + row) * 1024 + k0 + cc * 4);
      unsigned int pa0 = f2bf(va.x) | ((unsigned int)f2bf(va.y) << 16);
      unsigned int pa1 = f2bf(va.z) | ((unsigned int)f2bf(va.w) << 16);
      *(uint2*)&a_lds[row * 72 + cc * 4] = make_uint2(pa0, pa1);
      float4 vb = *(const float4*)(W + (size_t)(n0 + row) * 1024 + k0 + cc * 4);
      unsigned int pb0 = f2bf(vb.x) | ((unsigned int)f2bf(vb.y) << 16);
      unsigned int pb1 = f2bf(vb.z) | ((unsigned int)f2bf(vb.w) << 16);
      *(uint2*)&b_lds[row * 72 + cc * 4] = make_uint2(pb0, pb1);
    }
    __syncthreads();
#pragma unroll
    for (int ks = 0; ks < 2; ++ks) {
      bf16x8 af[4], bfr[4];
#pragma unroll
      for (int f = 0; f < 4; ++f) {
        af[f]  = *(const bf16x8*)&a_lds[(wm * 64 + f * 16 + (lane & 15)) * 72 + ks * 32 + (lane >> 4) * 8];
        bfr[f] = *(const bf16x8*)&b_lds[(wn * 64 + f * 16 + (lane & 15)) * 72 + ks * 32 + (lane >> 4) * 8];
      }
#pragma unroll
      for (int fi = 0; fi < 4; ++fi)
#pragma unroll
        for (int fj = 0; fj < 4; ++fj)
          acc[fi][fj] = __builtin_amdgcn_mfma_f32_16x16x32_bf16(af[fi], bfr[fj], acc[fi][fj], 0, 0, 0);
    }
    __syncthreads();
  }

  if (n0 < 2048) {
    // q/k region: repack via LDS, coalesced bf16 row stores
#pragma unroll
    for (int fi = 0; fi < 4; ++fi)
#pragma unroll
      for (int fj = 0; fj < 4; ++fj) {
        int row = wm * 64 + fi * 16 + ((lane >> 4) << 2);
        int col = wn * 64 + fj * 16 + (lane & 15);
#pragma unroll
        for (int r = 0; r < 4; ++r) smem[(row + r) * 136 + col] = f2bf(acc[fi][fj][r]);
      }
    __syncthreads();
#pragma unroll
    for (int i = 0; i < 8; ++i) {
      int c = i * 256 + tid;
      int row = c >> 4, cc = c & 15;
      *(int4*)(qk_ws + (size_t)(m0 + row) * 2048 + n0 + cc * 8) = *(const int4*)&smem[row * 136 + cc * 8];
    }
  } else {
    // v region: write transposed [bh][d][l]; frag rows are consecutive tokens -> 8B packs
#pragma unroll
    for (int fi = 0; fi < 4; ++fi)
#pragma unroll
      for (int fj = 0; fj < 4; ++fj) {
        int colg = n0 - 2048 + wn * 64 + fj * 16 + (lane & 15);
        int tok = m0 + wm * 64 + fi * 16 + ((lane >> 4) << 2);
        int bb = tok >> 11, lt = tok & 2047;
        int bh = bb * 16 + (colg >> 6);
        int dd = colg & 63;
        u32x2 pk;
        pk.x = f2bf(acc[fi][fj][0]) | ((unsigned int)f2bf(acc[fi][fj][1]) << 16);
        pk.y = f2bf(acc[fi][fj][2]) | ((unsigned int)f2bf(acc[fi][fj][3]) << 16);
        __builtin_nontemporal_store(pk, (u32x2*)(vt_ws + (size_t)(bh * 64 + dd) * 2048 + lt));
      }
  }
}

// ---------------- K2: attention. PASS 1 = rowsums, PASS 2 = attn write + PV ------
template <int PASS>
__global__ __launch_bounds__(256) void attn_k(
    const unsigned short* __restrict__ qk_ws, const unsigned short* __restrict__ vt_ws,
    float* __restrict__ rowsum, float* __restrict__ attn_out,
    unsigned short* __restrict__ ao_ws) {
  __shared__ unsigned short k_lds[64 * 72];
  __shared__ unsigned short v_lds[64 * 72];
  __shared__ unsigned short e_lds[32 * 72];
  __shared__ float ls_rs[32];

  const int tid = threadIdx.x;
  const int lane = tid & 63;
  const int w = tid >> 6;
  const int bh = blockIdx.y;           // b*16 + h
  const int b = bh >> 4;
  const int h = bh & 15;
  const int q0 = blockIdx.x * 32;

  // Q fragments (A operand of QK^T), held in registers for the whole kernel
  bf16x8 qf[2][2];
#pragma unroll
  for (int fi = 0; fi < 2; ++fi)
#pragma unroll
    for (int ks = 0; ks < 2; ++ks) {
      int tok = q0 + fi * 16 + (lane & 15);
      int col = h * 64 + ks * 32 + (lane >> 4) * 8;
      qf[fi][ks] = *(const bf16x8*)(qk_ws + ((size_t)(b * 2048 + tok)) * 2048 + col);
    }

  if (PASS == 1) {
    if (tid < 32) ls_rs[tid] = 0.f;
  } else {
    if (tid < 32) ls_rs[tid] = 1.0f / rowsum[(size_t)bh * 2048 + q0 + tid];
  }
  __syncthreads();

  float inv[2][4];
  if (PASS == 2) {
#pragma unroll
    for (int fi = 0; fi < 2; ++fi)
#pragma unroll
      for (int r = 0; r < 4; ++r) inv[fi][r] = ls_rs[fi * 16 + ((lane >> 4) << 2) + r];
  }

  float ps[2][4] = {{0.f, 0.f, 0.f, 0.f}, {0.f, 0.f, 0.f, 0.f}};
  f32x4 pv[2];
  pv[0] = (f32x4){0.f, 0.f, 0.f, 0.f};
  pv[1] = (f32x4){0.f, 0.f, 0.f, 0.f};

  for (int jt = 0; jt < 32; ++jt) {
    const int j0 = jt * 64;
    // stage K tile [64 j][64 d]; (pass2) V^T tile [64 d][64 j]
#pragma unroll
    for (int i = 0; i < 2; ++i) {
      int c = i * 256 + tid;
      int row = c >> 3, cc = c & 7;
      *(int4*)&k_lds[row * 72 + cc * 8] =
          *(const int4*)(qk_ws + ((size_t)(b * 2048 + j0 + row)) * 2048 + 1024 + h * 64 + cc * 8);
      if (PASS == 2)
        *(int4*)&v_lds[row * 72 + cc * 8] =
            *(const int4*)(vt_ws + ((size_t)(bh * 64 + row)) * 2048 + j0 + cc * 8);
    }
    __syncthreads();

    // QK^T for this wave's 16-col j slice
    f32x4 s[2];
    s[0] = (f32x4){0.f, 0.f, 0.f, 0.f};
    s[1] = (f32x4){0.f, 0.f, 0.f, 0.f};
    bf16x8 kf[2];
#pragma unroll
    for (int ks = 0; ks < 2; ++ks)
      kf[ks] = *(const bf16x8*)&k_lds[(w * 16 + (lane & 15)) * 72 + ks * 32 + (lane >> 4) * 8];
#pragma unroll
    for (int fi = 0; fi < 2; ++fi)
#pragma unroll
      for (int ks = 0; ks < 2; ++ks)
        s[fi] = __builtin_amdgcn_mfma_f32_16x16x32_bf16(qf[fi][ks], kf[ks], s[fi], 0, 0, 0);

    float e[2][4];
#pragma unroll
    for (int fi = 0; fi < 2; ++fi)
#pragma unroll
      for (int r = 0; r < 4; ++r) e[fi][r] = __expf(s[fi][r] * 0.125f);

    if (PASS == 1) {
#pragma unroll
      for (int fi = 0; fi < 2; ++fi)
#pragma unroll
        for (int r = 0; r < 4; ++r) ps[fi][r] += e[fi][r];
      __syncthreads();   // protect k_lds for next iteration
    } else {
      // normalized bf16 attn values into LDS (also the PV A-operand data)
#pragma unroll
      for (int fi = 0; fi < 2; ++fi) {
        int row = fi * 16 + ((lane >> 4) << 2);
        int col = w * 16 + (lane & 15);
#pragma unroll
        for (int r = 0; r < 4; ++r) e_lds[(row + r) * 72 + col] = f2bf(e[fi][r] * inv[fi][r]);
      }
      __syncthreads();

      // coalesced fp32 attn tile store: 32 rows x 64 cols (non-temporal: never re-read)
      {
        int row = tid >> 3;
        int c0 = (tid & 7) << 3;
        int4 raw = *(const int4*)&e_lds[row * 72 + c0];
        f32x4 o0, o1;
        o0.x = __uint_as_float(((unsigned int)raw.x) << 16);
        o0.y = __uint_as_float(((unsigned int)raw.x) & 0xffff0000u);
        o0.z = __uint_as_float(((unsigned int)raw.y) << 16);
        o0.w = __uint_as_float(((unsigned int)raw.y) & 0xffff0000u);
        o1.x = __uint_as_float(((unsigned int)raw.z) << 16);
        o1.y = __uint_as_float(((unsigned int)raw.z) & 0xffff0000u);
        o1.z = __uint_as_float(((unsigned int)raw.w) << 16);
        o1.w = __uint_as_float(((unsigned int)raw.w) & 0xffff0000u);
        size_t ab = ((size_t)bh * 2048 + q0 + row) * 2048 + j0 + c0;
        __builtin_nontemporal_store(o0, (f32x4*)(attn_out + ab));
        __builtin_nontemporal_store(o1, (f32x4*)(attn_out + ab + 4));
      }

      // PV: out^T[d][m] += v^T[d][j] * attn[m][j];  wave w owns d slice w*16..+15
#pragma unroll
      for (int ks = 0; ks < 2; ++ks) {
        bf16x8 vf = *(const bf16x8*)&v_lds[(w * 16 + (lane & 15)) * 72 + ks * 32 + (lane >> 4) * 8];
#pragma unroll
        for (int mf = 0; mf < 2; ++mf) {
          bf16x8 ef = *(const bf16x8*)&e_lds[(mf * 16 + (lane & 15)) * 72 + ks * 32 + (lane >> 4) * 8];
          pv[mf] = __builtin_amdgcn_mfma_f32_16x16x32_bf16(vf, ef, pv[mf], 0, 0, 0);
        }
      }
      __syncthreads();   // protect k/v/e LDS for next iteration
    }
  }

  if (PASS == 1) {
    // reduce partial rowsums over the 16 cols (lane&15) then across waves
#pragma unroll
    for (int fi = 0; fi < 2; ++fi)
#pragma unroll
      for (int r = 0; r < 4; ++r) {
        float v = ps[fi][r];
        v += __shfl_xor(v, 1);
        v += __shfl_xor(v, 2);
        v += __shfl_xor(v, 4);
        v += __shfl_xor(v, 8);
        if ((lane & 15) == 0) atomicAdd(&ls_rs[fi * 16 + ((lane >> 4) << 2) + r], v);
      }
    __syncthreads();
    if (tid < 32) rowsum[(size_t)bh * 2048 + q0 + tid] = ls_rs[tid];
  } else {
    // write ao (attention output before projection): lane has 4 consecutive d's
#pragma unroll
    for (int mf = 0; mf < 2; ++mf) {
      int tok = q0 + mf * 16 + (lane & 15);
      int d = w * 16 + ((lane >> 4) << 2);
      u32x2 pk;
      pk.x = f2bf(pv[mf][0]) | ((unsigned int)f2bf(pv[mf][1]) << 16);
      pk.y = f2bf(pv[mf][2]) | ((unsigned int)f2bf(pv[mf][3]) << 16);
      __builtin_nontemporal_store(pk, (u32x2*)(ao_ws + ((size_t)(b * 2048 + tok)) * 1024 + h * 64 + d));
    }
  }
}

// ---------------- K3: out = ao @ w_out^T + b_out  (M=4096, N=1024, K=1024) -------
__global__ __launch_bounds__(256) void gemm_out(
    const unsigned short* __restrict__ AO, const float* __restrict__ W,
    const float* __restrict__ Bias, float* __restrict__ OUT) {
  __shared__ unsigned short smem[2 * 128 * 72];
  unsigned short* a_lds = smem;
  unsigned short* b_lds = smem + 128 * 72;
  const int tid = threadIdx.x;
  const int lane = tid & 63;
  const int wid = tid >> 6;
  const int wm = wid >> 1, wn = wid & 1;
  const int m0 = blockIdx.x * 128, n0 = blockIdx.y * 128;

  f32x4 acc[4][4];
#pragma unroll
  for (int i = 0; i < 4; ++i)
#pragma unroll
    for (int j = 0; j < 4; ++j) acc[i][j] = (f32x4){0.f, 0.f, 0.f, 0.f};

  for (int kt = 0; kt < 16; ++kt) {
    const int k0 = kt * 64;
#pragma unroll
    for (int i = 0; i < 4; ++i) {                  // A already bf16
      int c = i * 256 + tid;
      int row = c >> 3, cc = c & 7;
      *(int4*)&a_lds[row * 72 + cc * 8] = *(const int4*)(AO + (size_t)(m0 + row) * 1024 + k0 + cc * 8);
    }
#pragma unroll
    for (int i = 0; i < 8; ++i) {                  // B fp32 -> bf16
      int c = i * 256 + tid;
      int row = c >> 4, cc = c & 15;
      float4 vb = *(const float4*)(W + (size_t)(n0 + row) * 1024 + k0 + cc * 4);
      unsigned int pb0 = f2bf(vb.x) | ((unsigned int)f2bf(vb.y) << 16);
      unsigned int pb1 = f2bf(vb.z) | ((unsigned int)f2bf(vb.w) << 16);
      *(uint2*)&b_lds[row * 72 + cc * 4] = make_uint2(pb0, pb1);
    }
    __syncthreads();
#pragma unroll
    for (int ks = 0; ks < 2; ++ks) {
      bf16x8 af[4], bfr[4];
#pragma unroll
      for (int f = 0; f < 4; ++f) {
        af[f]  = *(const bf16x8*)&a_lds[(wm * 64 + f * 16 + (lane & 15)) * 72 + ks * 32 + (lane >> 4) * 8];
        bfr[f] = *(const bf16x8*)&b_lds[(wn * 64 + f * 16 + (lane & 15)) * 72 + ks * 32 + (lane >> 4) * 8];
      }
#pragma unroll
      for (int fi = 0; fi < 4; ++fi)
#pragma unroll
        for (int fj = 0; fj < 4; ++fj)
          acc[fi][fj] = __builtin_amdgcn_mfma_f32_16x16x32_bf16(af[fi], bfr[fj], acc[fi][fj], 0, 0, 0);
    }
    __syncthreads();
  }

  // fp32 epilogue with bias, two 64-row halves through LDS for coalesced stores
  float* ftile = (float*)smem;
#pragma unroll
  for (int half = 0; half < 2; ++half) {
    if (wm == half) {
#pragma unroll
      for (int fi = 0; fi < 4; ++fi)
#pragma unroll
        for (int fj = 0; fj < 4; ++fj) {
          int row = fi * 16 + ((lane >> 4) << 2);
          int col = wn * 64 + fj * 16 + (lane & 15);
#pragma unroll
          for (int r = 0; r < 4; ++r) ftile[(row + r) * 136 + col] = acc[fi][fj][r];
        }
    }
    __syncthreads();
#pragma unroll
    for (int i = 0; i < 8; ++i) {
      int c = i * 256 + tid;
      int row = c >> 5, cc = c & 31;
      float4 v = *(const float4*)&ftile[row * 136 + cc * 4];
      float4 bb = *(const float4*)(Bias + n0 + cc * 4);
      v.x += bb.x; v.y += bb.y; v.z += bb.z; v.w += bb.w;
      *(float4*)(OUT + (size_t)(m0 + half * 64 + row) * 1024 + n0 + cc * 4) = v;
    }
    __syncthreads();
  }
}

extern "C" void kernel_launch(void* const* d_in, const int* in_sizes, int n_in,
                              void* d_out, int out_size, void* d_ws, size_t ws_size,
                              hipStream_t stream) {
  const float* x     = (const float*)d_in[0];   // [2,2048,1024]
  const float* w_qkv = (const float*)d_in[1];   // [3072,1024]
  const float* w_out = (const float*)d_in[2];   // [1024,1024]
  const float* b_out = (const float*)d_in[3];   // [1024]

  float* out      = (float*)d_out;                       // [2,2048,1024]
  float* attn_out = out + (size_t)4096 * 1024;           // [2,16,2048,2048]

  unsigned short* qk_ws = (unsigned short*)d_ws;                 // 16 MB
  unsigned short* vt_ws = qk_ws + (size_t)4096 * 2048;           //  8 MB
  unsigned short* ao_ws = vt_ws + (size_t)32 * 64 * 2048;        //  8 MB
  float* rowsum = (float*)(ao_ws + (size_t)4096 * 1024);         // 256 KB
  // total workspace: 33,816,576 bytes

  gemm_qkv<<<dim3(32, 24), 256, 0, stream>>>(x, w_qkv, qk_ws, vt_ws);
  attn_k<1><<<dim3(64, 32), 256, 0, stream>>>(qk_ws, vt_ws, rowsum, attn_out, ao_ws);
  attn_k<2><<<dim3(64, 32), 256, 0, stream>>>(qk_ws, vt_ws, rowsum, attn_out, ao_ws);
  gemm_out<<<dim3(32, 8), 256, 0, stream>>>(ao_ws, w_out, b_out, out);
}

// Round 7
// 702.275 us; speedup vs baseline: 1.4483x; 1.4483x over previous
//
#include <hip/hip_runtime.h>

// B=2, L=2048, E=1024, H=16, d=64.
// d_out: out [4096][1024] fp32, attn [32][2048][2048] fp32.
// Workspace (48 MB): qk_ws bf16[4096][2048] | vt_ws bf16[32][64][2048] |
//   ao_ws bf16[4096][1024] | xb bf16[4096][1024] | wqkvb bf16[3072][1024] | woutb bf16[1024][1024]

typedef __attribute__((ext_vector_type(8))) short bf16x8;
typedef __attribute__((ext_vector_type(4))) float f32x4;

__device__ __forceinline__ unsigned short f2bf(float f) {
  unsigned int u = __float_as_uint(f);
  u += 0x7fffu + ((u >> 16) & 1u);   // RNE
  return (unsigned short)(u >> 16);
}

// ---- K0: one-shot fp32 -> bf16 conversion of x, w_qkv, w_out (memory-bound) ----
__global__ __launch_bounds__(256) void conv_bf16(
    const float* __restrict__ X, const float* __restrict__ Wqkv, const float* __restrict__ Wout,
    unsigned short* __restrict__ xb, unsigned short* __restrict__ wqkvb,
    unsigned short* __restrict__ woutb) {
  size_t e0 = ((size_t)blockIdx.x * 256 + threadIdx.x) * 8;
  const float* src; unsigned short* dst; size_t off;
  if (e0 < 4194304)      { src = X;    dst = xb;    off = e0; }
  else if (e0 < 7340032) { src = Wqkv; dst = wqkvb; off = e0 - 4194304; }
  else                   { src = Wout; dst = woutb; off = e0 - 7340032; }
  float4 a = *(const float4*)(src + off);
  float4 c = *(const float4*)(src + off + 4);
  int4 o;
  o.x = f2bf(a.x) | ((unsigned int)f2bf(a.y) << 16);
  o.y = f2bf(a.z) | ((unsigned int)f2bf(a.w) << 16);
  o.z = f2bf(c.x) | ((unsigned int)f2bf(c.y) << 16);
  o.w = f2bf(c.z) | ((unsigned int)f2bf(c.w) << 16);
  *(int4*)(dst + off) = o;
}

// ---- K1: qkv = xb @ wqkvb^T (M=4096, N=3072, K=1024), bf16 staging ----
__global__ __launch_bounds__(256) void gemm_qkv(
    const unsigned short* __restrict__ XB, const unsigned short* __restrict__ WB,
    unsigned short* __restrict__ qk_ws, unsigned short* __restrict__ vt_ws) {
  __shared__ unsigned short smem[2 * 128 * 72];
  unsigned short* a_lds = smem;
  unsigned short* b_lds = smem + 128 * 72;
  const int tid = threadIdx.x;
  const int lane = tid & 63;
  const int wid = tid >> 6;
  const int wm = wid >> 1, wn = wid & 1;
  const int m0 = blockIdx.x * 128;
  const int n0 = blockIdx.y * 128;

  f32x4 acc[4][4];
#pragma unroll
  for (int i = 0; i < 4; ++i)
#pragma unroll
    for (int j = 0; j < 4; ++j) acc[i][j] = (f32x4){0.f, 0.f, 0.f, 0.f};

  for (int kt = 0; kt < 16; ++kt) {
    const int k0 = kt * 64;
#pragma unroll
    for (int i = 0; i < 4; ++i) {        // stage A and B tiles: 128x64 bf16, int4 loads
      int c = i * 256 + tid;
      int row = c >> 3, cc = (c & 7) << 3;
      *(int4*)&a_lds[row * 72 + cc] = *(const int4*)(XB + (size_t)(m0 + row) * 1024 + k0 + cc);
      *(int4*)&b_lds[row * 72 + cc] = *(const int4*)(WB + (size_t)(n0 + row) * 1024 + k0 + cc);
    }
    __syncthreads();
#pragma unroll
    for (int ks = 0; ks < 2; ++ks) {
      bf16x8 af[4], bfr[4];
#pragma unroll
      for (int f = 0; f < 4; ++f) {
        af[f]  = *(const bf16x8*)&a_lds[(wm * 64 + f * 16 + (lane & 15)) * 72 + ks * 32 + (lane >> 4) * 8];
        bfr[f] = *(const bf16x8*)&b_lds[(wn * 64 + f * 16 + (lane & 15)) * 72 + ks * 32 + (lane >> 4) * 8];
      }
#pragma unroll
      for (int fi = 0; fi < 4; ++fi)
#pragma unroll
        for (int fj = 0; fj < 4; ++fj)
          acc[fi][fj] = __builtin_amdgcn_mfma_f32_16x16x32_bf16(af[fi], bfr[fj], acc[fi][fj], 0, 0, 0);
    }
    __syncthreads();
  }

  if (n0 < 2048) {
    // q/k: repack via LDS, coalesced int4 row stores (re-read later -> regular stores)
#pragma unroll
    for (int fi = 0; fi < 4; ++fi)
#pragma unroll
      for (int fj = 0; fj < 4; ++fj) {
        int row = wm * 64 + fi * 16 + ((lane >> 4) << 2);
        int col = wn * 64 + fj * 16 + (lane & 15);
#pragma unroll
        for (int r = 0; r < 4; ++r) smem[(row + r) * 136 + col] = f2bf(acc[fi][fj][r]);
      }
    __syncthreads();
#pragma unroll
    for (int i = 0; i < 8; ++i) {
      int c = i * 256 + tid;
      int row = c >> 4, cc = c & 15;
      *(int4*)(qk_ws + (size_t)(m0 + row) * 2048 + n0 + cc * 8) = *(const int4*)&smem[row * 136 + cc * 8];
    }
  } else {
    // v: write transposed [bh][d][l]; 8B packs of 4 consecutive tokens (re-read -> regular)
#pragma unroll
    for (int fi = 0; fi < 4; ++fi)
#pragma unroll
      for (int fj = 0; fj < 4; ++fj) {
        int colg = n0 - 2048 + wn * 64 + fj * 16 + (lane & 15);
        int tok = m0 + wm * 64 + fi * 16 + ((lane >> 4) << 2);
        int bb = tok >> 11, lt = tok & 2047;
        int bh = bb * 16 + (colg >> 6);
        int dd = colg & 63;
        unsigned int p0 = f2bf(acc[fi][fj][0]) | ((unsigned int)f2bf(acc[fi][fj][1]) << 16);
        unsigned int p1 = f2bf(acc[fi][fj][2]) | ((unsigned int)f2bf(acc[fi][fj][3]) << 16);
        *(uint2*)(vt_ws + (size_t)(bh * 64 + dd) * 2048 + lt) = make_uint2(p0, p1);
      }
  }
}

// ---- K2: merged attention: phase1 rowsums, phase2 attn-write + PV ----
// Double-buffered LDS, register-prefetched staging (T14-style).
__global__ __launch_bounds__(256) void attn_merged(
    const unsigned short* __restrict__ qk_ws, const unsigned short* __restrict__ vt_ws,
    float* __restrict__ attn_out, unsigned short* __restrict__ ao_ws) {
  __shared__ unsigned short k_lds[2][64 * 72];
  __shared__ unsigned short v_lds[2][64 * 72];
  __shared__ unsigned short e_lds[32 * 72];
  __shared__ float ls_rs[32];

  const int tid = threadIdx.x;
  const int lane = tid & 63;
  const int w = tid >> 6;
  const int bh = blockIdx.y;
  const int b = bh >> 4;
  const int h = bh & 15;
  const int q0 = blockIdx.x * 32;

  const int srow = tid >> 3;            // staging: 8 threads/row, rows srow and srow+32
  const int scc = (tid & 7) << 3;
  const size_t kg = (size_t)(b * 2048) * 2048 + 1024 + (size_t)h * 64 + scc;  // + (j+row)*2048
  const size_t vg = ((size_t)(bh * 64 + srow)) * 2048 + scc;                  // + i*65536 + j0

  // Q fragments held for the whole kernel
  bf16x8 qf[2][2];
#pragma unroll
  for (int fi = 0; fi < 2; ++fi)
#pragma unroll
    for (int ks = 0; ks < 2; ++ks) {
      int tok = q0 + fi * 16 + (lane & 15);
      int col = h * 64 + ks * 32 + (lane >> 4) * 8;
      qf[fi][ks] = *(const bf16x8*)(qk_ws + ((size_t)(b * 2048 + tok)) * 2048 + col);
    }

  if (tid < 32) ls_rs[tid] = 0.f;

  // ================= phase 1: rowsums =================
  int4 ka, kb;
  ka = *(const int4*)(qk_ws + kg + (size_t)(srow) * 2048);
  kb = *(const int4*)(qk_ws + kg + (size_t)(32 + srow) * 2048);
  *(int4*)&k_lds[0][srow * 72 + scc] = ka;
  *(int4*)&k_lds[0][(32 + srow) * 72 + scc] = kb;
  ka = *(const int4*)(qk_ws + kg + (size_t)(64 + srow) * 2048);
  kb = *(const int4*)(qk_ws + kg + (size_t)(96 + srow) * 2048);
  __syncthreads();

  float ps[2][4] = {{0.f, 0.f, 0.f, 0.f}, {0.f, 0.f, 0.f, 0.f}};
  for (int jt = 0; jt < 32; ++jt) {
    const int cur = jt & 1;
    if (jt + 1 < 32) {                   // ds_write next tile from regs
      *(int4*)&k_lds[cur ^ 1][srow * 72 + scc] = ka;
      *(int4*)&k_lds[cur ^ 1][(32 + srow) * 72 + scc] = kb;
    }
    if (jt + 2 < 32) {                   // prefetch tile jt+2 into regs
      ka = *(const int4*)(qk_ws + kg + (size_t)((jt + 2) * 64 + srow) * 2048);
      kb = *(const int4*)(qk_ws + kg + (size_t)((jt + 2) * 64 + 32 + srow) * 2048);
    }
    bf16x8 kf0 = *(const bf16x8*)&k_lds[cur][(w * 16 + (lane & 15)) * 72 + (lane >> 4) * 8];
    bf16x8 kf1 = *(const bf16x8*)&k_lds[cur][(w * 16 + (lane & 15)) * 72 + 32 + (lane >> 4) * 8];
    f32x4 s0 = (f32x4){0.f, 0.f, 0.f, 0.f}, s1 = (f32x4){0.f, 0.f, 0.f, 0.f};
    s0 = __builtin_amdgcn_mfma_f32_16x16x32_bf16(qf[0][0], kf0, s0, 0, 0, 0);
    s0 = __builtin_amdgcn_mfma_f32_16x16x32_bf16(qf[0][1], kf1, s0, 0, 0, 0);
    s1 = __builtin_amdgcn_mfma_f32_16x16x32_bf16(qf[1][0], kf0, s1, 0, 0, 0);
    s1 = __builtin_amdgcn_mfma_f32_16x16x32_bf16(qf[1][1], kf1, s1, 0, 0, 0);
#pragma unroll
    for (int r = 0; r < 4; ++r) {
      ps[0][r] += __expf(s0[r] * 0.125f);
      ps[1][r] += __expf(s1[r] * 0.125f);
    }
    __syncthreads();
  }

#pragma unroll
  for (int fi = 0; fi < 2; ++fi)
#pragma unroll
    for (int r = 0; r < 4; ++r) {
      float v = ps[fi][r];
      v += __shfl_xor(v, 1);
      v += __shfl_xor(v, 2);
      v += __shfl_xor(v, 4);
      v += __shfl_xor(v, 8);
      if ((lane & 15) == 0) atomicAdd(&ls_rs[fi * 16 + ((lane >> 4) << 2) + r], v);
    }
  __syncthreads();
  float inv[2][4];
#pragma unroll
  for (int fi = 0; fi < 2; ++fi)
#pragma unroll
    for (int r = 0; r < 4; ++r) inv[fi][r] = 1.0f / ls_rs[fi * 16 + ((lane >> 4) << 2) + r];

  // ================= phase 2: attn write + PV =================
  f32x4 pv0 = (f32x4){0.f, 0.f, 0.f, 0.f}, pv1 = (f32x4){0.f, 0.f, 0.f, 0.f};
  int4 va, vb;
  ka = *(const int4*)(qk_ws + kg + (size_t)(srow) * 2048);
  kb = *(const int4*)(qk_ws + kg + (size_t)(32 + srow) * 2048);
  va = *(const int4*)(vt_ws + vg);
  vb = *(const int4*)(vt_ws + vg + 65536);
  *(int4*)&k_lds[0][srow * 72 + scc] = ka;
  *(int4*)&k_lds[0][(32 + srow) * 72 + scc] = kb;
  *(int4*)&v_lds[0][srow * 72 + scc] = va;
  *(int4*)&v_lds[0][(32 + srow) * 72 + scc] = vb;
  ka = *(const int4*)(qk_ws + kg + (size_t)(64 + srow) * 2048);
  kb = *(const int4*)(qk_ws + kg + (size_t)(96 + srow) * 2048);
  va = *(const int4*)(vt_ws + vg + 64);
  vb = *(const int4*)(vt_ws + vg + 65536 + 64);
  __syncthreads();

  for (int jt = 0; jt < 32; ++jt) {
    const int cur = jt & 1;
    const int j0 = jt * 64;
    if (jt + 1 < 32) {
      *(int4*)&k_lds[cur ^ 1][srow * 72 + scc] = ka;
      *(int4*)&k_lds[cur ^ 1][(32 + srow) * 72 + scc] = kb;
      *(int4*)&v_lds[cur ^ 1][srow * 72 + scc] = va;
      *(int4*)&v_lds[cur ^ 1][(32 + srow) * 72 + scc] = vb;
    }
    if (jt + 2 < 32) {
      ka = *(const int4*)(qk_ws + kg + (size_t)((jt + 2) * 64 + srow) * 2048);
      kb = *(const int4*)(qk_ws + kg + (size_t)((jt + 2) * 64 + 32 + srow) * 2048);
      va = *(const int4*)(vt_ws + vg + (jt + 2) * 64);
      vb = *(const int4*)(vt_ws + vg + 65536 + (jt + 2) * 64);
    }
    bf16x8 kf0 = *(const bf16x8*)&k_lds[cur][(w * 16 + (lane & 15)) * 72 + (lane >> 4) * 8];
    bf16x8 kf1 = *(const bf16x8*)&k_lds[cur][(w * 16 + (lane & 15)) * 72 + 32 + (lane >> 4) * 8];
    f32x4 s0 = (f32x4){0.f, 0.f, 0.f, 0.f}, s1 = (f32x4){0.f, 0.f, 0.f, 0.f};
    s0 = __builtin_amdgcn_mfma_f32_16x16x32_bf16(qf[0][0], kf0, s0, 0, 0, 0);
    s0 = __builtin_amdgcn_mfma_f32_16x16x32_bf16(qf[0][1], kf1, s0, 0, 0, 0);
    s1 = __builtin_amdgcn_mfma_f32_16x16x32_bf16(qf[1][0], kf0, s1, 0, 0, 0);
    s1 = __builtin_amdgcn_mfma_f32_16x16x32_bf16(qf[1][1], kf1, s1, 0, 0, 0);
    // normalized bf16 attn values into e_lds (PV A-operand data + store source)
    {
      int col = w * 16 + (lane & 15);
      int row0 = (lane >> 4) << 2;
#pragma unroll
      for (int r = 0; r < 4; ++r) {
        e_lds[(row0 + r) * 72 + col]      = f2bf(__expf(s0[r] * 0.125f) * inv[0][r]);
        e_lds[(16 + row0 + r) * 72 + col] = f2bf(__expf(s1[r] * 0.125f) * inv[1][r]);
      }
    }
    __syncthreads();
    // coalesced fp32 attn store (write-once -> non-temporal)
    {
      int row = tid >> 3;
      int c0 = (tid & 7) << 3;
      int4 raw = *(const int4*)&e_lds[row * 72 + c0];
      f32x4 o0, o1;
      o0.x = __uint_as_float(((unsigned int)raw.x) << 16);
      o0.y = __uint_as_float(((unsigned int)raw.x) & 0xffff0000u);
      o0.z = __uint_as_float(((unsigned int)raw.y) << 16);
      o0.w = __uint_as_float(((unsigned int)raw.y) & 0xffff0000u);
      o1.x = __uint_as_float(((unsigned int)raw.z) << 16);
      o1.y = __uint_as_float(((unsigned int)raw.z) & 0xffff0000u);
      o1.z = __uint_as_float(((unsigned int)raw.w) << 16);
      o1.w = __uint_as_float(((unsigned int)raw.w) & 0xffff0000u);
      size_t ab = ((size_t)bh * 2048 + q0 + row) * 2048 + j0 + c0;
      __builtin_nontemporal_store(o0, (f32x4*)(attn_out + ab));
      __builtin_nontemporal_store(o1, (f32x4*)(attn_out + ab + 4));
    }
    // PV: out^T[d][m] += v^T[d][j] * attn[m][j]
#pragma unroll
    for (int ks = 0; ks < 2; ++ks) {
      bf16x8 vf  = *(const bf16x8*)&v_lds[cur][(w * 16 + (lane & 15)) * 72 + ks * 32 + (lane >> 4) * 8];
      bf16x8 ef0 = *(const bf16x8*)&e_lds[((lane & 15)) * 72 + ks * 32 + (lane >> 4) * 8];
      bf16x8 ef1 = *(const bf16x8*)&e_lds[(16 + (lane & 15)) * 72 + ks * 32 + (lane >> 4) * 8];
      pv0 = __builtin_amdgcn_mfma_f32_16x16x32_bf16(vf, ef0, pv0, 0, 0, 0);
      pv1 = __builtin_amdgcn_mfma_f32_16x16x32_bf16(vf, ef1, pv1, 0, 0, 0);
    }
    __syncthreads();
  }

  // ao (pre-projection attention output), re-read by gemm_out -> regular stores
#pragma unroll
  for (int mf = 0; mf < 2; ++mf) {
    f32x4 pv = mf ? pv1 : pv0;
    int tok = q0 + mf * 16 + (lane & 15);
    int d = w * 16 + ((lane >> 4) << 2);
    unsigned int p0 = f2bf(pv[0]) | ((unsigned int)f2bf(pv[1]) << 16);
    unsigned int p1 = f2bf(pv[2]) | ((unsigned int)f2bf(pv[3]) << 16);
    *(uint2*)(ao_ws + ((size_t)(b * 2048 + tok)) * 1024 + h * 64 + d) = make_uint2(p0, p1);
  }
}

// ---- K3: out = ao @ woutb^T + b_out (M=4096, N=1024, K=1024), bf16 staging ----
__global__ __launch_bounds__(256) void gemm_out(
    const unsigned short* __restrict__ AO, const unsigned short* __restrict__ WB,
    const float* __restrict__ Bias, float* __restrict__ OUT) {
  __shared__ unsigned short smem[2 * 128 * 72];
  unsigned short* a_lds = smem;
  unsigned short* b_lds = smem + 128 * 72;
  const int tid = threadIdx.x;
  const int lane = tid & 63;
  const int wid = tid >> 6;
  const int wm = wid >> 1, wn = wid & 1;
  const int m0 = blockIdx.x * 128, n0 = blockIdx.y * 128;

  f32x4 acc[4][4];
#pragma unroll
  for (int i = 0; i < 4; ++i)
#pragma unroll
    for (int j = 0; j < 4; ++j) acc[i][j] = (f32x4){0.f, 0.f, 0.f, 0.f};

  for (int kt = 0; kt < 16; ++kt) {
    const int k0 = kt * 64;
#pragma unroll
    for (int i = 0; i < 4; ++i) {
      int c = i * 256 + tid;
      int row = c >> 3, cc = (c & 7) << 3;
      *(int4*)&a_lds[row * 72 + cc] = *(const int4*)(AO + (size_t)(m0 + row) * 1024 + k0 + cc);
      *(int4*)&b_lds[row * 72 + cc] = *(const int4*)(WB + (size_t)(n0 + row) * 1024 + k0 + cc);
    }
    __syncthreads();
#pragma unroll
    for (int ks = 0; ks < 2; ++ks) {
      bf16x8 af[4], bfr[4];
#pragma unroll
      for (int f = 0; f < 4; ++f) {
        af[f]  = *(const bf16x8*)&a_lds[(wm * 64 + f * 16 + (lane & 15)) * 72 + ks * 32 + (lane >> 4) * 8];
        bfr[f] = *(const bf16x8*)&b_lds[(wn * 64 + f * 16 + (lane & 15)) * 72 + ks * 32 + (lane >> 4) * 8];
      }
#pragma unroll
      for (int fi = 0; fi < 4; ++fi)
#pragma unroll
        for (int fj = 0; fj < 4; ++fj)
          acc[fi][fj] = __builtin_amdgcn_mfma_f32_16x16x32_bf16(af[fi], bfr[fj], acc[fi][fj], 0, 0, 0);
    }
    __syncthreads();
  }

  float* ftile = (float*)smem;
#pragma unroll
  for (int half = 0; half < 2; ++half) {
    if (wm == half) {
#pragma unroll
      for (int fi = 0; fi < 4; ++fi)
#pragma unroll
        for (int fj = 0; fj < 4; ++fj) {
          int row = fi * 16 + ((lane >> 4) << 2);
          int col = wn * 64 + fj * 16 + (lane & 15);
#pragma unroll
          for (int r = 0; r < 4; ++r) ftile[(row + r) * 136 + col] = acc[fi][fj][r];
        }
    }
    __syncthreads();
#pragma unroll
    for (int i = 0; i < 8; ++i) {
      int c = i * 256 + tid;
      int row = c >> 5, cc = c & 31;
      float4 v = *(const float4*)&ftile[row * 136 + cc * 4];
      float4 bb = *(const float4*)(Bias + n0 + cc * 4);
      v.x += bb.x; v.y += bb.y; v.z += bb.z; v.w += bb.w;
      *(float4*)(OUT + (size_t)(m0 + half * 64 + row) * 1024 + n0 + cc * 4) = v;
    }
    __syncthreads();
  }
}

extern "C" void kernel_launch(void* const* d_in, const int* in_sizes, int n_in,
                              void* d_out, int out_size, void* d_ws, size_t ws_size,
                              hipStream_t stream) {
  const float* x     = (const float*)d_in[0];   // [2,2048,1024]
  const float* w_qkv = (const float*)d_in[1];   // [3072,1024]
  const float* w_out = (const float*)d_in[2];   // [1024,1024]
  const float* b_out = (const float*)d_in[3];   // [1024]

  float* out      = (float*)d_out;
  float* attn_out = out + (size_t)4096 * 1024;

  unsigned short* qk_ws = (unsigned short*)d_ws;               // 16 MB
  unsigned short* vt_ws = qk_ws + (size_t)4096 * 2048;         //  8 MB
  unsigned short* ao_ws = vt_ws + (size_t)32 * 64 * 2048;      //  8 MB
  unsigned short* xb    = ao_ws + (size_t)4096 * 1024;         //  8 MB
  unsigned short* wqkvb = xb + (size_t)4096 * 1024;            //  6 MB
  unsigned short* woutb = wqkvb + (size_t)3072 * 1024;         //  2 MB
  // total workspace: 48 MB

  conv_bf16<<<4096, 256, 0, stream>>>(x, w_qkv, w_out, xb, wqkvb, woutb);
  gemm_qkv<<<dim3(32, 24), 256, 0, stream>>>(xb, wqkvb, qk_ws, vt_ws);
  attn_merged<<<dim3(64, 32), 256, 0, stream>>>(qk_ws, vt_ws, attn_out, ao_ws);
  gemm_out<<<dim3(32, 8), 256, 0, stream>>>(ao_ws, woutb, b_out, out);
}